// Round 27
// baseline (39.678 us; speedup 1.0000x reference)
//
#include <hip/hip_runtime.h>

// B=64, H=W=512, K=7, VALID conv -> 506x506.
// v27 = v17-proven masked step discipline (no garbage taps, direct slot map)
//       + v26's load mechanism: 8 cols/lane DISJOINT loads (2 dwordx4/row)
//         and __shfl_down for the 6 neighbor floats; ONE 512-col strip.
//       + rule-#18 fence: sched_barrier(0) after EVERY inline-asm waitcnt
//         (v26's failure: compiler moved register-only FMAs/shuffles across
//         the asm vmcnt wait; ties alone don't pin them).
// Wave = 512 cols x 8 rows (14 input rows); block = 4 waves = 32 rows.
// FMA = exactly 49/output (masked warmup/tail); line-touches 3x below v25.
#define HW 512
#define OW 506

typedef float vf4 __attribute__((ext_vector_type(4)));

// 2 disjoint global_load_dwordx4; "=&v" early-clobber (v15 fault fix).
#define LOAD_ROW2(d0, d1, addr)                                       \
    asm volatile("global_load_dwordx4 %0, %2, off\n\t"                \
                 "global_load_dwordx4 %1, %2, off offset:16"          \
                 : "=&v"(d0), "=&v"(d1)                               \
                 : "v"(addr) : "memory")

// Counted wait; tied "+v" pins the SSA values, sched_barrier(0) pins the
// SCHEDULER (rule #18: ties alone don't stop motion across asm waitcnt).
#define WAIT_ROW2(d0, d1, N)                                          \
    do {                                                              \
        asm volatile("s_waitcnt vmcnt(" #N ")"                        \
                     : "+v"(d0), "+v"(d1));                           \
        __builtin_amdgcn_sched_barrier(0);                            \
    } while (0)

template<int R>
__device__ __forceinline__ void step(vf4 (&B0)[4], vf4 (&B1)[4],
                                     const float*& ap, float* op,
                                     const float (&wv)[49],
                                     float (&acc)[8][8],
                                     bool ok1, bool ok2, bool ok3) {
    constexpr int s3 = R & 3;
    WAIT_ROW2(B0[s3], B1[s3], 6);

    float sh[6];
    sh[0] = __shfl_down(B0[s3][0], 1, 64);
    sh[1] = __shfl_down(B0[s3][1], 1, 64);
    sh[2] = __shfl_down(B0[s3][2], 1, 64);
    sh[3] = __shfl_down(B0[s3][3], 1, 64);
    sh[4] = __shfl_down(B1[s3][0], 1, 64);
    sh[5] = __shfl_down(B1[s3][1], 1, 64);

    // masked taps: output s = R - kr must lie in [0,7] -> no garbage ever.
    constexpr int klo = (R - 7 > 0) ? (R - 7) : 0;
    constexpr int khi = (R < 6) ? R : 6;
#pragma unroll
    for (int kr = klo; kr <= khi; ++kr) {
        const int s = R - kr;                    // 0..7, static
#pragma unroll
        for (int kc = 0; kc < 7; ++kc) {
            const float wk = wv[kr * 7 + kc];
#pragma unroll
            for (int j = 0; j < 8; ++j) {
                const int e = kc + j;            // 0..13, static
                const float v = (e < 4) ? B0[s3][e]
                              : (e < 8) ? B1[s3][e - 4] : sh[e - 8];
                acc[s][j] = fmaf(wk, v, acc[s][j]);
            }
        }
    }

    if constexpr (R >= 6) {                      // output row R-6 complete
        constexpr int s = R - 6;
        float* orow = op + s * OW;               // 8B aligned (cb mult of 8)
        *reinterpret_cast<float2*>(orow) = make_float2(acc[s][0], acc[s][1]);
        if (ok1) *reinterpret_cast<float2*>(orow + 2) =
            make_float2(acc[s][2], acc[s][3]);
        if (ok2) *reinterpret_cast<float2*>(orow + 4) =
            make_float2(acc[s][4], acc[s][5]);
        if (ok3) *reinterpret_cast<float2*>(orow + 6) =
            make_float2(acc[s][6], acc[s][7]);
    }
    if constexpr (R <= 9) {                      // load row R+4 (4..13)
        LOAD_ROW2(B0[s3], B1[s3], ap);
        ap += HW;
    }
}

__global__ __launch_bounds__(256) void conv7x7_v27(
    const float* __restrict__ in,      // [64][512][512]
    const float* __restrict__ weight,  // [7][7]
    const float* __restrict__ bias,    // [1]
    float* __restrict__ out)           // [64][506][506]
{
    const int tid  = threadIdx.x;
    const int lane = tid & 63;
    const int w    = tid >> 6;
    const int band = blockIdx.x;                 // 0..15
    const int b    = blockIdx.y;                 // image
    const int y0   = min(band * 32, OW - 32);    // last band shifted to 474
    const int yb   = y0 + 8 * w;                 // wave's first output row (<=498)

    // ---- weights + bias -> SGPRs (uniform, statically indexed) ----
    float wv[49];
#pragma unroll
    for (int i = 0; i < 49; ++i)
        wv[i] = __uint_as_float(__builtin_amdgcn_readfirstlane(__float_as_uint(weight[i])));
    const float bv = __uint_as_float(__builtin_amdgcn_readfirstlane(__float_as_uint(bias[0])));

    const int cb = 8 * lane;                     // first output col (<=504)
    // loads: rows yb..yb+13 <= 511; cols cb..cb+7 <= 511 -- all in-bounds.
    const float* ap = in  + (size_t)b * (HW * HW) + (size_t)yb * HW + cb;
    float*       op = out + (size_t)b * (OW * OW) + (size_t)yb * OW + cb;

    // store-pair guards (false only in lane 63; pair0 always valid: 505<506)
    const bool ok1 = (cb + 3) < OW;
    const bool ok2 = (cb + 5) < OW;
    const bool ok3 = (cb + 7) < OW;

    vf4 B0[4], B1[4];                            // 4-row rotating buffer
    float acc[8][8];                             // direct slot map: acc[s]
#pragma unroll
    for (int i = 0; i < 8; ++i)
#pragma unroll
        for (int j = 0; j < 8; ++j) acc[i][j] = bv;   // bias folded in

    // ---- prologue: rows 0..3 -> 8 loads in flight ----
    LOAD_ROW2(B0[0], B1[0], ap); ap += HW;
    LOAD_ROW2(B0[1], B1[1], ap); ap += HW;
    LOAD_ROW2(B0[2], B1[2], ap); ap += HW;
    LOAD_ROW2(B0[3], B1[3], ap); ap += HW;

    // ---- 14 fully-static steps (input rows 0..13) ----
    step<0>(B0, B1, ap, op, wv, acc, ok1, ok2, ok3);
    step<1>(B0, B1, ap, op, wv, acc, ok1, ok2, ok3);
    step<2>(B0, B1, ap, op, wv, acc, ok1, ok2, ok3);
    step<3>(B0, B1, ap, op, wv, acc, ok1, ok2, ok3);
    step<4>(B0, B1, ap, op, wv, acc, ok1, ok2, ok3);
    step<5>(B0, B1, ap, op, wv, acc, ok1, ok2, ok3);
    step<6>(B0, B1, ap, op, wv, acc, ok1, ok2, ok3);
    step<7>(B0, B1, ap, op, wv, acc, ok1, ok2, ok3);
    step<8>(B0, B1, ap, op, wv, acc, ok1, ok2, ok3);
    step<9>(B0, B1, ap, op, wv, acc, ok1, ok2, ok3);
    step<10>(B0, B1, ap, op, wv, acc, ok1, ok2, ok3);
    step<11>(B0, B1, ap, op, wv, acc, ok1, ok2, ok3);
    step<12>(B0, B1, ap, op, wv, acc, ok1, ok2, ok3);
    step<13>(B0, B1, ap, op, wv, acc, ok1, ok2, ok3);
}

extern "C" void kernel_launch(void* const* d_in, const int* in_sizes, int n_in,
                              void* d_out, int out_size, void* d_ws, size_t ws_size,
                              hipStream_t stream) {
    const float* enc_x  = (const float*)d_in[0];
    const float* weight = (const float*)d_in[1];
    const float* bias   = (const float*)d_in[2];
    float* outp         = (float*)d_out;

    // x: 16 bands of 32 rows (last shifted to 474); y: 64 images.
    // ONE 512-col strip (64 lanes x 8 cols). 1024 blocks = 4/CU.
    dim3 grid(16, 64);
    dim3 block(256);
    hipLaunchKernelGGL(conv7x7_v27, grid, block, 0, stream,
                       enc_x, weight, bias, outp);
}